// Round 1
// baseline (31.681 us; speedup 1.0000x reference)
//
#include <hip/hip_runtime.h>
#include <math.h>

// Problem constants (from reference init)
#define NB     16      // N
#define PB     4       // P
#define LTAPS  16      // L
#define SS     128     // S = Ns + N_pilot
#define MM     1024    // Mk = OPT_M

__device__ __constant__ float C_LIGHT  = 3.0e8f;
#define TWO_PI_F 6.28318530717958647692f

// ---------------------------------------------------------------------------
// Kernel 1: out[n,p,s,m] = x[n,p,s,m] * factor[n,p,s]
//   factor[s] = sum_l cof[l] * exp(-i * phase_coef[l] * (delay1[l] + delay2[s]))
// One block per (n,p,s); 256 threads stream M=1024 complex values via float4.
// ---------------------------------------------------------------------------
__global__ __launch_bounds__(256) void main_kernel(
    const float* __restrict__ in,   // (N,P,S*M,2) f32
    const float* __restrict__ cof,  // (N,P,L) f32, strictly positive
    float* __restrict__ out)        // (N,P,S*M,2) f32
{
    const int bid = blockIdx.x;          // 0 .. N*P*S-1
    const int np  = bid >> 7;            // / S
    const int s   = bid & (SS - 1);      // % S
    const int t   = threadIdx.x;

    __shared__ float lre[LTAPS], lim[LTAPS];

    if (t < LTAPS) {
        const float cofl   = cof[np * LTAPS + t];
        // delay1 = -100*log(cof)/c
        const float delay1 = (-100.0f * logf(cofl)) / C_LIGHT;
        // delay2[s] = s * 0.0005/14  (linspace step)
        const float delay2 = (0.0005f / 14.0f) * (float)s;
        // phase_coef[l] = 2*pi*cos(2*pi*l/15) * max_doppler, max_doppler = 1000
        const float angle  = (TWO_PI_F / 15.0f) * (float)t;
        const float pc     = TWO_PI_F * cosf(angle) * 1000.0f;
        const float ph     = pc * (delay1 + delay2);
        float sn, cs;
        sincosf(ph, &sn, &cs);
        lre[t] = cofl * cs;              // real of cof * exp(-i*ph)
        lim[t] = -cofl * sn;             // imag
    }
    __syncthreads();

    // broadcast-sum the 16 taps (same-address LDS reads broadcast: free)
    float fre = 0.0f, fim = 0.0f;
#pragma unroll
    for (int l = 0; l < LTAPS; ++l) { fre += lre[l]; fim += lim[l]; }

    // stream M complex values: float4 = 2 complex (re,im,re,im)
    const float4* __restrict__ in4  = (const float4*)in  + (size_t)bid * (MM / 2);
    float4* __restrict__       out4 = (float4*)out       + (size_t)bid * (MM / 2);

#pragma unroll
    for (int j = t; j < MM / 2; j += 256) {
        const float4 v = in4[j];
        float4 r;
        r.x = v.x * fre - v.y * fim;
        r.y = v.x * fim + v.y * fre;
        r.z = v.z * fre - v.w * fim;
        r.w = v.z * fim + v.w * fre;
        out4[j] = r;
    }
}

// ---------------------------------------------------------------------------
// Kernel 2: H_t[n,p,k] = sum_l cof[l] * exp(-2*pi*i*k*l/M),  k = 0..M-1
// (FFT of zero-padded taps == 16-tap direct DFT). One block per (n,p).
// ---------------------------------------------------------------------------
__global__ __launch_bounds__(256) void ht_kernel(
    const float* __restrict__ cof,  // (N,P,L)
    float* __restrict__ ht)         // (N,P,M,2)
{
    const int np = blockIdx.x;      // 0 .. N*P-1
    const int t  = threadIdx.x;

    __shared__ float c[LTAPS];
    if (t < LTAPS) c[t] = cof[np * LTAPS + t];
    __syncthreads();

    float2* __restrict__ o = (float2*)ht + (size_t)np * MM;

    for (int k = t; k < MM; k += 256) {
        float re = 0.0f, im = 0.0f;
#pragma unroll
        for (int l = 0; l < LTAPS; ++l) {
            const float ang = (TWO_PI_F / (float)MM) * (float)(k * l);
            float sn, cs;
            sincosf(ang, &sn, &cs);
            re += c[l] * cs;
            im -= c[l] * sn;
        }
        o[k] = make_float2(re, im);
    }
}

// ---------------------------------------------------------------------------
extern "C" void kernel_launch(void* const* d_in, const int* in_sizes, int n_in,
                              void* d_out, int out_size, void* d_ws, size_t ws_size,
                              hipStream_t stream)
{
    const float* in  = (const float*)d_in[0];   // input_ri (N,P,S*M,2)
    const float* cof = (const float*)d_in[1];   // cof (N,P,L)
    float* out = (float*)d_out;                              // out_ri first
    float* ht  = out + (size_t)NB * PB * SS * MM * 2;        // then H_t_ri

    hipLaunchKernelGGL(main_kernel, dim3(NB * PB * SS), dim3(256), 0, stream,
                       in, cof, out);
    hipLaunchKernelGGL(ht_kernel, dim3(NB * PB), dim3(256), 0, stream,
                       cof, ht);
}

// Round 2
// 30.858 us; speedup vs baseline: 1.0266x; 1.0266x over previous
//
#include <hip/hip_runtime.h>
#include <math.h>

// Problem constants (from reference init)
#define NB     16      // N
#define PB     4       // P
#define LTAPS  16      // L
#define SS     128     // S = Ns + N_pilot
#define MM     1024    // Mk = OPT_M

#define TWO_PI_F 6.28318530717958647692f

// ---------------------------------------------------------------------------
// Kernel A (fused small work, one thread per output element):
//  blocks [0, FAC_BLKS):  factor[np,s] = sum_l cof[l]*exp(-i*pc_l*(d1_l + d2_s))
//  blocks [FAC_BLKS, ..): H_t[np,k]    = sum_l cof[l]*exp(-2*pi*i*k*l/M)
// ---------------------------------------------------------------------------
#define FAC_BLKS  32                    // 32*256 = 8192 = NB*PB*SS
#define HT_BLKS   256                   // 256*256 = 65536 = NB*PB*MM

__global__ __launch_bounds__(256) void small_kernel(
    const float* __restrict__ cof,      // (N,P,L) f32, strictly positive
    float* __restrict__ fac,            // (N*P*S) float2 in d_ws
    float* __restrict__ ht)             // (N,P,M,2) f32 tail of d_out
{
    const int b = blockIdx.x;
    const int t = threadIdx.x;

    if (b < FAC_BLKS) {
        const int id = b * 256 + t;     // (np, s)
        const int np = id >> 7;
        const int s  = id & (SS - 1);
        const float delay2 = (0.0005f / 14.0f) * (float)s;
        float fre = 0.0f, fim = 0.0f;
#pragma unroll
        for (int l = 0; l < LTAPS; ++l) {
            const float cofl   = cof[np * LTAPS + l];
            const float delay1 = (-100.0f / 3.0e8f) * logf(cofl);
            const float angle  = (TWO_PI_F / 15.0f) * (float)l;
            const float pc     = TWO_PI_F * cosf(angle) * 1000.0f;
            const float ph     = pc * (delay1 + delay2);
            float sn, cs;
            sincosf(ph, &sn, &cs);
            fre += cofl * cs;
            fim -= cofl * sn;
        }
        ((float2*)fac)[id] = make_float2(fre, fim);
    } else {
        const int id = (b - FAC_BLKS) * 256 + t;   // (np, k)
        const int np = id >> 10;
        const int k  = id & (MM - 1);
        float re = 0.0f, im = 0.0f;
#pragma unroll
        for (int l = 0; l < LTAPS; ++l) {
            const float ang = (TWO_PI_F / (float)MM) * (float)(k * l);
            float sn, cs;
            sincosf(ang, &sn, &cs);
            const float c = cof[np * LTAPS + l];
            re += c * cs;
            im -= c * sn;
        }
        ((float2*)ht)[id] = make_float2(re, im);
    }
}

// ---------------------------------------------------------------------------
// Kernel B: pure streaming. out4[g] = in4[g] * fac[g>>9]
// (512 float4 per (np,s); fac is a 64 KB L1/L2-resident table, wave-broadcast)
// ---------------------------------------------------------------------------
#define TOT4 (NB * PB * SS * MM / 2)    // total float4 elements = 4194304

__global__ __launch_bounds__(256) void main_kernel(
    const float* __restrict__ in,       // (N,P,S*M,2) f32
    const float* __restrict__ fac,      // (N*P*S) float2
    float* __restrict__ out)            // (N,P,S*M,2) f32
{
    const float2* __restrict__ f2 = (const float2*)fac;
    const float4* __restrict__ in4 = (const float4*)in;
    float4* __restrict__ out4 = (float4*)out;

    const int stride = gridDim.x * 256;
    for (int g = blockIdx.x * 256 + threadIdx.x; g < TOT4; g += stride) {
        const float2 f = f2[g >> 9];
        const float4 v = in4[g];
        float4 r;
        r.x = v.x * f.x - v.y * f.y;
        r.y = v.x * f.y + v.y * f.x;
        r.z = v.z * f.x - v.w * f.y;
        r.w = v.z * f.y + v.w * f.x;
        out4[g] = r;
    }
}

// ---------------------------------------------------------------------------
extern "C" void kernel_launch(void* const* d_in, const int* in_sizes, int n_in,
                              void* d_out, int out_size, void* d_ws, size_t ws_size,
                              hipStream_t stream)
{
    const float* in  = (const float*)d_in[0];   // input_ri (N,P,S*M,2)
    const float* cof = (const float*)d_in[1];   // cof (N,P,L)
    float* out = (float*)d_out;                              // out_ri first
    float* ht  = out + (size_t)NB * PB * SS * MM * 2;        // then H_t_ri
    float* fac = (float*)d_ws;                               // 8192 float2 = 64 KB

    hipLaunchKernelGGL(small_kernel, dim3(FAC_BLKS + HT_BLKS), dim3(256), 0, stream,
                       cof, fac, ht);
    hipLaunchKernelGGL(main_kernel, dim3(2048), dim3(256), 0, stream,
                       in, fac, out);
}

// Round 3
// 28.662 us; speedup vs baseline: 1.1053x; 1.0766x over previous
//
#include <hip/hip_runtime.h>
#include <math.h>

// Problem constants (from reference init)
#define NB     16      // N
#define PB     4       // P
#define LTAPS  16      // L
#define SS     128     // S = Ns + N_pilot
#define MM     1024    // Mk = OPT_M

#define TWO_PI_F 6.28318530717958647692f

#define STREAM_BLKS 2048                 // 2048*256 threads * 8 float4 = TOT4
#define HT_BLKS     256                  // 256*256 = 65536 = NB*PB*MM
#define TOT4 (NB * PB * SS * MM / 2)     // 4194304 float4

// ---------------------------------------------------------------------------
// Single fused kernel.
//  blocks [0, STREAM_BLKS):  out4[g] = in4[g] * fac[g>>9]
//      Each block needs fac at exactly 8 indices: (b>>1) + k*1024, k=0..7.
//      128-thread preamble computes the 8x16 tap terms, LDS-reduces them.
//  blocks [STREAM_BLKS, +HT_BLKS): H_t[np,k] = sum_l cof[l] * w^l,
//      w = exp(-2*pi*i*k/M)  (1 sincos + 15 complex FMAs, runs concurrently
//      with the memory-bound streaming blocks).
// ---------------------------------------------------------------------------
__global__ __launch_bounds__(256) void fused_kernel(
    const float* __restrict__ in,   // (N,P,S*M,2) f32
    const float* __restrict__ cof,  // (N,P,L)    f32, strictly positive
    float* __restrict__ out,        // (N,P,S*M,2) f32
    float* __restrict__ ht)         // (N,P,M,2)  f32
{
    const int b = blockIdx.x;
    const int t = threadIdx.x;

    if (b < STREAM_BLKS) {
        __shared__ float term_re[128], term_im[128];
        __shared__ float2 facs[8];

        const int base = b >> 1;                 // (b*256+t)>>9, t<256
        if (t < 128) {
            const int k  = t >> 4;               // which of the 8 fac values
            const int l  = t & 15;               // tap index
            const int id = base + k * 1024;      // flattened (np,s), < 8192
            const int np = id >> 7;
            const int s  = id & (SS - 1);
            const float cofl   = cof[np * LTAPS + l];
            const float delay1 = (-100.0f / 3.0e8f) * logf(cofl);
            const float delay2 = (0.0005f / 14.0f) * (float)s;
            const float pc     = TWO_PI_F * 1000.0f * cosf((TWO_PI_F / 15.0f) * (float)l);
            const float ph     = pc * (delay1 + delay2);
            float sn, cs;
            sincosf(ph, &sn, &cs);
            term_re[t] = cofl * cs;
            term_im[t] = -cofl * sn;
        }
        __syncthreads();
        if (t < 8) {
            float re = 0.0f, im = 0.0f;
#pragma unroll
            for (int l = 0; l < LTAPS; ++l) {
                re += term_re[t * 16 + l];
                im += term_im[t * 16 + l];
            }
            facs[t] = make_float2(re, im);
        }
        __syncthreads();

        const float4* __restrict__ in4  = (const float4*)in;
        float4* __restrict__       out4 = (float4*)out;
        int g = b * 256 + t;
#pragma unroll
        for (int k = 0; k < 8; ++k, g += STREAM_BLKS * 256) {
            const float2 f = facs[k];
            const float4 v = in4[g];
            float4 r;
            r.x = v.x * f.x - v.y * f.y;
            r.y = v.x * f.y + v.y * f.x;
            r.z = v.z * f.x - v.w * f.y;
            r.w = v.z * f.y + v.w * f.x;
            out4[g] = r;
        }
    } else {
        const int id = (b - STREAM_BLKS) * 256 + t;  // (np, k)
        const int np = id >> 10;
        const int k  = id & (MM - 1);
        float sn, cs;
        sincosf((TWO_PI_F / (float)MM) * (float)k, &sn, &cs);
        const float wr = cs, wi = -sn;               // w = exp(-2*pi*i*k/M)
        const float* __restrict__ c = cof + np * LTAPS;
        float hr = 0.0f, hi = 0.0f;                  // H accumulator
        float cr = 1.0f, ci = 0.0f;                  // w^l
#pragma unroll
        for (int l = 0; l < LTAPS; ++l) {
            const float cl = c[l];
            hr += cl * cr;
            hi += cl * ci;
            const float nr = cr * wr - ci * wi;
            const float ni = cr * wi + ci * wr;
            cr = nr; ci = ni;
        }
        ((float2*)ht)[id] = make_float2(hr, hi);
    }
}

// ---------------------------------------------------------------------------
extern "C" void kernel_launch(void* const* d_in, const int* in_sizes, int n_in,
                              void* d_out, int out_size, void* d_ws, size_t ws_size,
                              hipStream_t stream)
{
    const float* in  = (const float*)d_in[0];   // input_ri (N,P,S*M,2)
    const float* cof = (const float*)d_in[1];   // cof (N,P,L)
    float* out = (float*)d_out;                              // out_ri first
    float* ht  = out + (size_t)NB * PB * SS * MM * 2;        // then H_t_ri

    hipLaunchKernelGGL(fused_kernel, dim3(STREAM_BLKS + HT_BLKS), dim3(256), 0, stream,
                       in, cof, out, ht);
}

// Round 5
// 26.589 us; speedup vs baseline: 1.1915x; 1.0780x over previous
//
#include <hip/hip_runtime.h>
#include <math.h>

// Problem constants (from reference init)
#define NB     16      // N
#define PB     4       // P
#define LTAPS  16      // L
#define SS     128     // S = Ns + N_pilot
#define MM     1024    // Mk = OPT_M

#define TWO_PI_F 6.28318530717958647692f

#define HT_BLKS     256                  // 256*256 = 65536 = NB*PB*MM (run FIRST)
#define STREAM_BLKS 2048                 // 2048 blocks * 2048 float4 = TOT4
#define TOT4 (NB * PB * SS * MM / 2)     // 4194304 float4

typedef float f32x4 __attribute__((ext_vector_type(4)));
typedef float f32x2 __attribute__((ext_vector_type(2)));

// ---------------------------------------------------------------------------
// Single fused kernel, HT blocks FIRST so their VALU-bound work overlaps the
// memory-bound streaming blocks instead of forming a serialized tail.
//
//  blocks [0, HT_BLKS):  H_t[np,k] = sum_l cof[l] * w^l, w = exp(-2pi*i*k/M)
//      (1 sincos + 15 complex FMAs via power recurrence)
//  blocks [HT_BLKS, +STREAM_BLKS): contiguous 2048-float4 chunk per block
//      = 4 consecutive (np,s) rows; 64-thread preamble computes the 4 factor
//      values (one tap term per thread, LDS reduce), then pure streaming.
// ---------------------------------------------------------------------------
__global__ __launch_bounds__(256) void fused_kernel(
    const float* __restrict__ in,   // (N,P,S*M,2) f32
    const float* __restrict__ cof,  // (N,P,L)    f32, strictly positive
    float* __restrict__ out,        // (N,P,S*M,2) f32
    float* __restrict__ ht)         // (N,P,M,2)  f32
{
    const int b = blockIdx.x;
    const int t = threadIdx.x;

    if (b >= HT_BLKS) {
        const int sb = b - HT_BLKS;              // streaming block id
        __shared__ float term_re[64], term_im[64];
        __shared__ f32x2 facs[4];

        if (t < 64) {
            const int j  = t >> 4;               // which of the 4 fac values
            const int l  = t & 15;               // tap index
            const int id = sb * 4 + j;           // flattened (np,s), < 8192
            const int np = id >> 7;
            const int s  = id & (SS - 1);
            const float cofl   = cof[np * LTAPS + l];
            const float delay1 = (-100.0f / 3.0e8f) * logf(cofl);
            const float delay2 = (0.0005f / 14.0f) * (float)s;
            const float pc     = TWO_PI_F * 1000.0f * cosf((TWO_PI_F / 15.0f) * (float)l);
            const float ph     = pc * (delay1 + delay2);
            float sn, cs;
            sincosf(ph, &sn, &cs);
            term_re[t] = cofl * cs;
            term_im[t] = -cofl * sn;
        }
        __syncthreads();
        if (t < 4) {
            float re = 0.0f, im = 0.0f;
#pragma unroll
            for (int l = 0; l < LTAPS; ++l) {
                re += term_re[t * 16 + l];
                im += term_im[t * 16 + l];
            }
            f32x2 f; f.x = re; f.y = im;
            facs[t] = f;
        }
        __syncthreads();

        const f32x4* __restrict__ in4  = (const f32x4*)in + (size_t)sb * 2048;
        f32x4* __restrict__       out4 = (f32x4*)out      + (size_t)sb * 2048;
#pragma unroll
        for (int k = 0; k < 8; ++k) {
            const int   idx = k * 256 + t;       // 0..2047 within chunk
            const f32x2 f   = facs[k >> 1];      // 512 float4 per (np,s)
            const f32x4 v   = __builtin_nontemporal_load(&in4[idx]);
            f32x4 r;
            r.x = v.x * f.x - v.y * f.y;
            r.y = v.x * f.y + v.y * f.x;
            r.z = v.z * f.x - v.w * f.y;
            r.w = v.z * f.y + v.w * f.x;
            __builtin_nontemporal_store(r, &out4[idx]);
        }
    } else {
        const int id = b * 256 + t;              // (np, k)
        const int np = id >> 10;
        const int k  = id & (MM - 1);
        float sn, cs;
        sincosf((TWO_PI_F / (float)MM) * (float)k, &sn, &cs);
        const float wr = cs, wi = -sn;           // w = exp(-2*pi*i*k/M)
        const float* __restrict__ c = cof + np * LTAPS;
        float hr = 0.0f, hi = 0.0f;              // H accumulator
        float cr = 1.0f, ci = 0.0f;              // w^l
#pragma unroll
        for (int l = 0; l < LTAPS; ++l) {
            const float cl = c[l];
            hr += cl * cr;
            hi += cl * ci;
            const float nr = cr * wr - ci * wi;
            const float ni = cr * wi + ci * wr;
            cr = nr; ci = ni;
        }
        float2* __restrict__ o = (float2*)ht;
        o[id] = make_float2(hr, hi);
    }
}

// ---------------------------------------------------------------------------
extern "C" void kernel_launch(void* const* d_in, const int* in_sizes, int n_in,
                              void* d_out, int out_size, void* d_ws, size_t ws_size,
                              hipStream_t stream)
{
    const float* in  = (const float*)d_in[0];   // input_ri (N,P,S*M,2)
    const float* cof = (const float*)d_in[1];   // cof (N,P,L)
    float* out = (float*)d_out;                              // out_ri first
    float* ht  = out + (size_t)NB * PB * SS * MM * 2;        // then H_t_ri

    hipLaunchKernelGGL(fused_kernel, dim3(HT_BLKS + STREAM_BLKS), dim3(256), 0, stream,
                       in, cof, out, ht);
}

// Round 6
// 25.547 us; speedup vs baseline: 1.2401x; 1.0408x over previous
//
#include <hip/hip_runtime.h>
#include <math.h>

// Problem constants (from reference init)
#define NB     16      // N
#define PB     4       // P
#define LTAPS  16      // L
#define SS     128     // S = Ns + N_pilot
#define MM     1024    // Mk = OPT_M

#define TWO_PI_F 6.28318530717958647692f

#define HT_BLKS     256                  // 256*256 = 65536 = NB*PB*MM (run FIRST)
#define STREAM_BLKS 2048                 // 2048 blocks * 2048 float4 = TOT4
#define TOT4 (NB * PB * SS * MM / 2)     // 4194304 float4

typedef float f32x4 __attribute__((ext_vector_type(4)));

// ---------------------------------------------------------------------------
// Single fused kernel, HT blocks FIRST so their VALU-bound work overlaps the
// memory-bound streaming blocks instead of forming a serialized tail.
//
//  blocks [0, HT_BLKS):  H_t[np,k] = sum_l cof[l] * w^l, w = exp(-2pi*i*k/M)
//      (1 sincos + 15 complex FMAs via power recurrence)
//  blocks [HT_BLKS, +STREAM_BLKS): contiguous 2048-float4 chunk per block
//      = 4 consecutive (np,s) rows. Loads are issued FIRST; the 4 factor
//      values are then computed redundantly per-wave with an in-wave
//      __shfl reduction (no LDS, no __syncthreads, no vmcnt-drain points).
// ---------------------------------------------------------------------------
__global__ __launch_bounds__(256) void fused_kernel(
    const float* __restrict__ in,   // (N,P,S*M,2) f32
    const float* __restrict__ cof,  // (N,P,L)    f32, strictly positive
    float* __restrict__ out,        // (N,P,S*M,2) f32
    float* __restrict__ ht)         // (N,P,M,2)  f32
{
    const int b = blockIdx.x;
    const int t = threadIdx.x;

    if (b >= HT_BLKS) {
        const int sb = b - HT_BLKS;              // streaming block id

        // ---- issue all 8 loads first (independent of factor preamble) ----
        const f32x4* __restrict__ in4  = (const f32x4*)in + (size_t)sb * 2048;
        f32x4* __restrict__       out4 = (f32x4*)out      + (size_t)sb * 2048;
        f32x4 v[8];
#pragma unroll
        for (int k = 0; k < 8; ++k)
            v[k] = __builtin_nontemporal_load(&in4[k * 256 + t]);

        // ---- per-wave redundant factor computation (barrier-free) ----
        // lane = (j,l): j = which of the 4 (np,s) rows, l = tap index
        const int lane = t & 63;
        const int j    = lane >> 4;
        const int l    = lane & 15;
        const int id   = sb * 4 + j;             // flattened (np,s), < 8192
        const int np   = id >> 7;
        const int s    = id & (SS - 1);
        const float cofl   = cof[np * LTAPS + l];
        const float delay1 = (-100.0f / 3.0e8f) * logf(cofl);
        const float delay2 = (0.0005f / 14.0f) * (float)s;
        const float pc     = TWO_PI_F * 1000.0f * cosf((TWO_PI_F / 15.0f) * (float)l);
        const float ph     = pc * (delay1 + delay2);
        float sn, cs;
        sincosf(ph, &sn, &cs);
        float re = cofl * cs;
        float im = -cofl * sn;
        // reduce the 16 taps within each 16-lane group
#pragma unroll
        for (int w = 1; w < 16; w <<= 1) {
            re += __shfl_xor(re, w);
            im += __shfl_xor(im, w);
        }
        // broadcast the 4 group sums to every lane
        float fre[4], fim[4];
#pragma unroll
        for (int jj = 0; jj < 4; ++jj) {
            fre[jj] = __shfl(re, jj * 16);
            fim[jj] = __shfl(im, jj * 16);
        }

        // ---- multiply + store as loads return ----
#pragma unroll
        for (int k = 0; k < 8; ++k) {
            const int jj = k >> 1;               // 512 float4 per (np,s)
            f32x4 r;
            r.x = v[k].x * fre[jj] - v[k].y * fim[jj];
            r.y = v[k].x * fim[jj] + v[k].y * fre[jj];
            r.z = v[k].z * fre[jj] - v[k].w * fim[jj];
            r.w = v[k].z * fim[jj] + v[k].w * fre[jj];
            __builtin_nontemporal_store(r, &out4[k * 256 + t]);
        }
    } else {
        const int id = b * 256 + t;              // (np, k)
        const int np = id >> 10;
        const int k  = id & (MM - 1);
        float sn, cs;
        sincosf((TWO_PI_F / (float)MM) * (float)k, &sn, &cs);
        const float wr = cs, wi = -sn;           // w = exp(-2*pi*i*k/M)
        const float* __restrict__ c = cof + np * LTAPS;
        float hr = 0.0f, hi = 0.0f;              // H accumulator
        float cr = 1.0f, ci = 0.0f;              // w^l
#pragma unroll
        for (int l = 0; l < LTAPS; ++l) {
            const float cl = c[l];
            hr += cl * cr;
            hi += cl * ci;
            const float nr = cr * wr - ci * wi;
            const float ni = cr * wi + ci * wr;
            cr = nr; ci = ni;
        }
        float2* __restrict__ o = (float2*)ht;
        o[id] = make_float2(hr, hi);
    }
}

// ---------------------------------------------------------------------------
extern "C" void kernel_launch(void* const* d_in, const int* in_sizes, int n_in,
                              void* d_out, int out_size, void* d_ws, size_t ws_size,
                              hipStream_t stream)
{
    const float* in  = (const float*)d_in[0];   // input_ri (N,P,S*M,2)
    const float* cof = (const float*)d_in[1];   // cof (N,P,L)
    float* out = (float*)d_out;                              // out_ri first
    float* ht  = out + (size_t)NB * PB * SS * MM * 2;        // then H_t_ri

    hipLaunchKernelGGL(fused_kernel, dim3(HT_BLKS + STREAM_BLKS), dim3(256), 0, stream,
                       in, cof, out, ht);
}